// Round 6
// baseline (181.995 us; speedup 1.0000x reference)
//
#include <hip/hip_runtime.h>
#include <math.h>

#define T_  4
#define B_  16
#define C_  384
#define HW_ 256
#define E_  8

typedef __attribute__((ext_vector_type(8))) __bf16 bf16x8;
typedef __attribute__((ext_vector_type(4))) float f32x4;

union FragU { uint4 u; bf16x8 v; };

// taus = jnp.linspace(1.5, 4.0, 8) in fp32, endpoint exact
__device__ __forceinline__ float tau_of(int e) {
    if (e == 7) return 4.0f;
    const float delta = 2.5f / 7.0f;
    return __fadd_rn(1.5f, __fmul_rn((float)e, delta));
}

// bits of m (8 spikes) -> bf16x8 {0,1} fragment
__device__ __forceinline__ FragU expand_mask(unsigned m) {
    FragU f;
    f.u.x = ((m & 1u)   ? 0x3F80u : 0u) | ((m & 2u)   ? 0x3F800000u : 0u);
    f.u.y = ((m & 4u)   ? 0x3F80u : 0u) | ((m & 8u)   ? 0x3F800000u : 0u);
    f.u.z = ((m & 16u)  ? 0x3F80u : 0u) | ((m & 32u)  ? 0x3F800000u : 0u);
    f.u.w = ((m & 64u)  ? 0x3F80u : 0u) | ((m & 128u) ? 0x3F800000u : 0u);
    return f;
}

// ---------------- k_prep: fused weight-split + router LIF (unchanged R5) ----
__global__ __launch_bounds__(256) void k_prep(const float* __restrict__ x,
        const float* __restrict__ W1, const float* __restrict__ W2,
        unsigned short* __restrict__ Whif, unsigned short* __restrict__ Wlof,
        float* __restrict__ m) {
    if (blockIdx.x < 1152) {
        int tid = blockIdx.x * 256 + threadIdx.x;    // 294912 total
        int l = tid & 63;
        int f = tid >> 6;                            // 0..4607
        int osub = f % 24;
        int ksub = (f / 24) % 12;
        int cv = (f / 288) & 1;
        int e = f / 576;
        const float* Wsrc = (cv == 0 ? W1 : W2) + (size_t)e * C_ * C_;
        int o = osub * 16 + (l & 15);
        int c0 = ksub * 32 + (l >> 4) * 8;
        const float* src = Wsrc + (size_t)o * C_ + c0;
        unsigned hw[8], lw[8];
#pragma unroll
        for (int j = 0; j < 8; ++j) {
            float w = src[j];
            unsigned u = __float_as_uint(w);
            unsigned hi = (u + 0x7FFFu + ((u >> 16) & 1u)) >> 16;
            float hf = __uint_as_float(hi << 16);
            float res = __fsub_rn(w, hf);
            unsigned ru = __float_as_uint(res);
            unsigned lo = (ru + 0x7FFFu + ((ru >> 16) & 1u)) >> 16;
            hw[j] = hi & 0xFFFFu;
            lw[j] = lo & 0xFFFFu;
        }
        size_t dst = (size_t)f * 512 + (size_t)l * 8;
        uint4 hv = make_uint4(hw[0] | (hw[1] << 16), hw[2] | (hw[3] << 16),
                              hw[4] | (hw[5] << 16), hw[6] | (hw[7] << 16));
        uint4 lv = make_uint4(lw[0] | (lw[1] << 16), lw[2] | (lw[3] << 16),
                              lw[4] | (lw[5] << 16), lw[6] | (lw[7] << 16));
        *reinterpret_cast<uint4*>(Whif + dst) = hv;
        *reinterpret_cast<uint4*>(Wlof + dst) = lv;
    } else {
        int bc = blockIdx.x - 1152;
        int b = bc / C_, c = bc % C_;
        int p = threadIdx.x;
        int wv = threadIdx.x >> 6;
        __shared__ int cnt[T_][4];
        float v = 0.0f;
#pragma unroll
        for (int t = 0; t < T_; ++t) {
            float xv = x[((t * B_ + b) * C_ + c) * HW_ + p];
            v = __fadd_rn(v, __fdiv_rn(__fsub_rn(xv, v), 2.0f));
            bool s = (__fsub_rn(v, 1.0f) >= 0.0f);
            if (s) v = 0.0f;
            unsigned long long mask = __ballot(s);
            if ((threadIdx.x & 63) == 0) cnt[t][wv] = (int)__popcll(mask);
        }
        __syncthreads();
        if (threadIdx.x < T_) {
            int t = threadIdx.x;
            int tot = cnt[t][0] + cnt[t][1] + cnt[t][2] + cnt[t][3];
            m[(t * B_ + b) * C_ + c] = (float)tot * 0.00390625f;
        }
    }
}

// ---------------- conv core: software-pipelined lo/hi MFMA over 12 ksub ------
__device__ __forceinline__ void conv_mfma(const unsigned short* __restrict__ Whif,
                                          const unsigned short* __restrict__ Wlof,
                                          unsigned base,
                                          const unsigned char* __restrict__ sm,
                                          f32x4 (&acc)[3][4],
                                          int tw, int lane, int q, int pl) {
    const unsigned lane8 = (unsigned)lane * 8u;
    const unsigned wbase = base + (unsigned)(tw * 3) * 512u + lane8;
    FragU c0f, c1f, c2f, n0f, n1f, n2f;
    c0f.u = *reinterpret_cast<const uint4*>(Wlof + wbase);
    c1f.u = *reinterpret_cast<const uint4*>(Wlof + wbase + 512u);
    c2f.u = *reinterpret_cast<const uint4*>(Wlof + wbase + 1024u);
#pragma unroll 1
    for (int ksub = 0; ksub < 12; ++ksub) {
        unsigned fo = wbase + (unsigned)ksub * 24u * 512u;
        FragU bf[T_];
#pragma unroll
        for (int t = 0; t < T_; ++t) {
            unsigned mbyte = sm[(t * 16 + pl) * 48 + ksub * 4 + q];
            bf[t] = expand_mask(mbyte);
        }
        n0f.u = *reinterpret_cast<const uint4*>(Whif + fo);
        n1f.u = *reinterpret_cast<const uint4*>(Whif + fo + 512u);
        n2f.u = *reinterpret_cast<const uint4*>(Whif + fo + 1024u);
#pragma unroll
        for (int t = 0; t < T_; ++t) {
            acc[0][t] = __builtin_amdgcn_mfma_f32_16x16x32_bf16(c0f.v, bf[t].v, acc[0][t], 0, 0, 0);
            acc[1][t] = __builtin_amdgcn_mfma_f32_16x16x32_bf16(c1f.v, bf[t].v, acc[1][t], 0, 0, 0);
            acc[2][t] = __builtin_amdgcn_mfma_f32_16x16x32_bf16(c2f.v, bf[t].v, acc[2][t], 0, 0, 0);
        }
        if (ksub < 11) {
            unsigned fn = fo + 24u * 512u;
            c0f.u = *reinterpret_cast<const uint4*>(Wlof + fn);
            c1f.u = *reinterpret_cast<const uint4*>(Wlof + fn + 512u);
            c2f.u = *reinterpret_cast<const uint4*>(Wlof + fn + 1024u);
        }
#pragma unroll
        for (int t = 0; t < T_; ++t) {
            acc[0][t] = __builtin_amdgcn_mfma_f32_16x16x32_bf16(n0f.v, bf[t].v, acc[0][t], 0, 0, 0);
            acc[1][t] = __builtin_amdgcn_mfma_f32_16x16x32_bf16(n1f.v, bf[t].v, acc[1][t], 0, 0, 0);
            acc[2][t] = __builtin_amdgcn_mfma_f32_16x16x32_bf16(n2f.v, bf[t].v, acc[2][t], 0, 0, 0);
        }
    }
}

// ---------------- k_expert: rank-team fused MoE block -----------------------
// grid 256 blocks (b x ptile), 1024 threads = 2 teams x 8 waves. Team r runs
// expert rank r end-to-end; combine via LDS staging (team1) + unique writer
// (team0). 16 waves/CU = 4 waves/SIMD.
__global__ __launch_bounds__(1024, 4) void k_expert(
        const float* __restrict__ x, const float* __restrict__ m,
        const float* __restrict__ rW, const float* __restrict__ rb,
        const float* __restrict__ rbs, const float* __restrict__ rbb,
        const unsigned short* __restrict__ Whif, const unsigned short* __restrict__ Wlof,
        const float* __restrict__ b1, const float* __restrict__ s1sc, const float* __restrict__ s1bi,
        const float* __restrict__ b2, const float* __restrict__ s2sc, const float* __restrict__ s2bi,
        float* __restrict__ out) {
    int blk = blockIdx.x;
    int b = (blk & 7) | (((blk >> 3) & 1) << 3);
    int ptile = blk >> 4;

    __shared__ unsigned char s1m[2][T_ * 16 * 48];
    __shared__ unsigned char s2m[2][T_ * 16 * 48];
    __shared__ float bns[2 * 6 * C_];      // [rank][A1,B1,BB1,A2,B2,BB2][o]
    __shared__ float lds_part[512 * 49];   // team1 contribs, stride 49 (conflict-free)
    __shared__ float lg[E_];
    __shared__ float wsl[2];
    __shared__ int esl[2];

    int tid = threadIdx.x;
    int team = tid >> 9;                 // 0 / 1  (wave-uniform)
    int tid2 = tid & 511;                // team-local thread
    int tw = tid2 >> 6;                  // team-local wave 0..7
    int lane = tid & 63;
    int q = lane >> 4;
    int pl = lane & 15;
    int p = ptile * 16 + pl;
    float denom = sqrtf(__fadd_rn(1.0f, 1e-5f));

    // ---- inline route (first wave), identical arithmetic to R5
    if (tid < 64) {
        int combo = tid & 31, half = tid >> 5;
        int e = combo >> 2, t = combo & 3;
        float dot = 0.0f;
        int c0 = half * 192;
        for (int c = 0; c < 192; ++c)
            dot = fmaf(rW[e * C_ + c0 + c], m[(t * B_ + b) * C_ + c0 + c], dot);
        dot += __shfl_down(dot, 32);
        float Ar = __fdiv_rn(rbs[e], denom);
        float lt = __fadd_rn(__fmul_rn(__fadd_rn(dot, rb[e]), Ar), rbb[e]);
        lt = __fadd_rn(lt, __shfl_xor(lt, 1));
        lt = __fadd_rn(lt, __shfl_xor(lt, 2));
        if (half == 0 && t == 0) lg[e] = __fmul_rn(lt, 0.25f);
    }
    __syncthreads();
    if (tid == 0) {
        float pr[E_];
        float mx = lg[0];
        for (int i = 1; i < E_; ++i) mx = fmaxf(mx, lg[i]);
        float s = 0.0f;
        for (int i = 0; i < E_; ++i) { pr[i] = expf(__fsub_rn(lg[i], mx)); s = __fadd_rn(s, pr[i]); }
        for (int i = 0; i < E_; ++i) pr[i] = __fdiv_rn(pr[i], s);
        int i0 = 0;
        for (int i = 1; i < E_; ++i) if (pr[i] > pr[i0]) i0 = i;
        int i1 = (i0 == 0) ? 1 : 0;
        for (int i = 0; i < E_; ++i) if (i != i0 && pr[i] > pr[i1]) i1 = i;
        float s2 = __fadd_rn(pr[i0], pr[i1]);
        wsl[0] = __fdiv_rn(pr[i0], s2);
        wsl[1] = __fdiv_rn(pr[i1], s2);
        esl[0] = i0;
        esl[1] = i1;
    }
    __syncthreads();

    int er = esl[team];
    float wgt = wsl[team];
    float tau = tau_of(er);

    // ---- BN staging for both ranks (768 threads)
    if (tid < 2 * C_) {
        int r_ = tid / C_;
        int o = tid % C_;
        int eo = esl[r_] * C_ + o;
        bns[(r_ * 6 + 0) * C_ + o] = __fdiv_rn(s1sc[eo], denom);
        bns[(r_ * 6 + 1) * C_ + o] = b1[eo];
        bns[(r_ * 6 + 2) * C_ + o] = s1bi[eo];
        bns[(r_ * 6 + 3) * C_ + o] = __fdiv_rn(s2sc[eo], denom);
        bns[(r_ * 6 + 4) * C_ + o] = b2[eo];
        bns[(r_ * 6 + 5) * C_ + o] = s2bi[eo];
    }

    // ---- LIF1 (team-local tau) -> byte masks s1m[team]
#pragma unroll 1
    for (int task = tid2; task < 48 * 16; task += 512) {
        int cb = task >> 4;
        int tpl = task & 15;
        int tp = ptile * 16 + tpl;
        float v[8];
#pragma unroll
        for (int j = 0; j < 8; ++j) v[j] = 0.0f;
#pragma unroll
        for (int t = 0; t < T_; ++t) {
            int gbase = ((t * B_ + b) * C_ + cb * 8) * HW_ + tp;
            unsigned mb = 0;
#pragma unroll
            for (int j = 0; j < 8; ++j) {
                float xv = x[gbase + j * HW_];
                v[j] = __fadd_rn(v[j], __fdiv_rn(__fsub_rn(xv, v[j]), tau));
                if (__fsub_rn(v[j], 1.0f) >= 0.0f) { mb |= (1u << j); v[j] = 0.0f; }
            }
            s1m[team][(t * 16 + tpl) * 48 + cb] = (unsigned char)mb;
        }
    }
    __syncthreads();

    const unsigned base1 = (unsigned)(er * 2) * 12u * 24u * 512u;
    const unsigned base2 = (unsigned)(er * 2 + 1) * 12u * 24u * 512u;

    // =================== conv1 (own rank) ===================
    {
        f32x4 acc[3][4];
#pragma unroll
        for (int os = 0; os < 3; ++os)
#pragma unroll
            for (int t = 0; t < T_; ++t) acc[os][t] = (f32x4)0.0f;

        conv_mfma(Whif, Wlof, base1, &s1m[team][0], acc, tw, lane, q, pl);

        // epilogue: h = x + bn1(y); contrib = wgt*h -> out (team0) / LDS (team1);
        // LIF2 -> s2m[team]
#pragma unroll
        for (int os = 0; os < 3; ++os) {
            float v2s[4] = {0.f, 0.f, 0.f, 0.f};
#pragma unroll
            for (int t = 0; t < T_; ++t) {
                unsigned nb = 0;
#pragma unroll
                for (int r = 0; r < 4; ++r) {
                    int o = tw * 48 + os * 16 + q * 4 + r;
                    int gi = ((t * B_ + b) * C_ + o) * HW_ + p;
                    float y = acc[os][t][r];
                    float h = __fadd_rn(x[gi],
                        __fadd_rn(__fmul_rn(__fadd_rn(y, bns[(team * 6 + 1) * C_ + o]),
                                            bns[(team * 6 + 0) * C_ + o]),
                                  bns[(team * 6 + 2) * C_ + o]));
                    float contrib = __fmul_rn(wgt, h);
                    if (team == 0) out[gi] = contrib;
                    else lds_part[tid2 * 49 + os * 16 + t * 4 + r] = contrib;
                    v2s[r] = __fadd_rn(v2s[r], __fdiv_rn(__fsub_rn(h, v2s[r]), tau));
                    if (__fsub_rn(v2s[r], 1.0f) >= 0.0f) { nb |= (1u << r); v2s[r] = 0.f; }
                }
                unsigned nb_hi = (unsigned)__shfl_down((int)nb, 16);
                if ((q & 1) == 0) {
                    int cbyte = tw * 6 + os * 2 + (q >> 1);
                    s2m[team][(t * 16 + pl) * 48 + cbyte] = (unsigned char)(nb | (nb_hi << 4));
                }
            }
        }
    }
    __syncthreads();

    // =================== conv2 (own rank) ===================
    {
        f32x4 acc[3][4];
#pragma unroll
        for (int os = 0; os < 3; ++os)
#pragma unroll
            for (int t = 0; t < T_; ++t) acc[os][t] = (f32x4)0.0f;

        conv_mfma(Whif, Wlof, base2, &s2m[team][0], acc, tw, lane, q, pl);

        // epilogue: val = wgt*bn2(y)
        // team1: lds_part += val; team0: hold val in regs (reuse acc) until combine
#pragma unroll
        for (int os = 0; os < 3; ++os)
#pragma unroll
            for (int t = 0; t < T_; ++t)
#pragma unroll
                for (int r = 0; r < 4; ++r) {
                    int o = tw * 48 + os * 16 + q * 4 + r;
                    float y = acc[os][t][r];
                    float val = __fmul_rn(wgt,
                        __fadd_rn(__fmul_rn(__fadd_rn(y, bns[(team * 6 + 4) * C_ + o]),
                                            bns[(team * 6 + 3) * C_ + o]),
                                  bns[(team * 6 + 5) * C_ + o]));
                    if (team == 1) {
                        int li = tid2 * 49 + os * 16 + t * 4 + r;
                        lds_part[li] = __fadd_rn(lds_part[li], val);
                    } else {
                        acc[os][t][r] = val;   // keep for combine
                    }
                }
        __syncthreads();

        // ---- final combine: team0 folds out_prev + val0 + team1's staged part
        if (team == 0) {
#pragma unroll
            for (int os = 0; os < 3; ++os)
#pragma unroll
                for (int t = 0; t < T_; ++t)
#pragma unroll
                    for (int r = 0; r < 4; ++r) {
                        int o = tw * 48 + os * 16 + q * 4 + r;
                        int gi = ((t * B_ + b) * C_ + o) * HW_ + p;
                        float pp = lds_part[tid2 * 49 + os * 16 + t * 4 + r];
                        out[gi] = __fadd_rn(__fadd_rn(out[gi], acc[os][t][r]), pp);
                    }
        }
    }
}

extern "C" void kernel_launch(void* const* d_in, const int* in_sizes, int n_in,
                              void* d_out, int out_size, void* d_ws, size_t ws_size,
                              hipStream_t stream) {
    const float* x    = (const float*)d_in[0];
    const float* rW   = (const float*)d_in[1];
    const float* rb   = (const float*)d_in[2];
    const float* rbs  = (const float*)d_in[3];
    const float* rbb  = (const float*)d_in[4];
    const float* W1   = (const float*)d_in[5];
    const float* b1   = (const float*)d_in[6];
    const float* s1sc = (const float*)d_in[7];
    const float* s1bi = (const float*)d_in[8];
    const float* W2   = (const float*)d_in[9];
    const float* b2   = (const float*)d_in[10];
    const float* s2sc = (const float*)d_in[11];
    const float* s2bi = (const float*)d_in[12];
    float* out = (float*)d_out;

    // ws layout: Whif (4718592 B) | Wlof (4718592 B) | m (24576 floats)
    unsigned short* Whif = (unsigned short*)d_ws;
    unsigned short* Wlof = Whif + 2359296;
    float* m = (float*)((char*)d_ws + 9437184);

    hipLaunchKernelGGL(k_prep, dim3(1152 + B_ * C_), dim3(256), 0, stream,
                       x, W1, W2, Whif, Wlof, m);
    hipLaunchKernelGGL(k_expert, dim3(256), dim3(1024), 0, stream,
                       x, m, rW, rb, rbs, rbb, Whif, Wlof,
                       b1, s1sc, s1bi, b2, s2sc, s2bi, out);
}

// Round 7
// 173.253 us; speedup vs baseline: 1.0505x; 1.0505x over previous
//
#include <hip/hip_runtime.h>
#include <math.h>

#define T_  4
#define B_  16
#define C_  384
#define HW_ 256
#define E_  8

typedef __attribute__((ext_vector_type(8))) __bf16 bf16x8;
typedef __attribute__((ext_vector_type(4))) float f32x4;

union FragU { uint4 u; bf16x8 v; };

// taus = jnp.linspace(1.5, 4.0, 8) in fp32, endpoint exact
__device__ __forceinline__ float tau_of(int e) {
    if (e == 7) return 4.0f;
    const float delta = 2.5f / 7.0f;
    return __fadd_rn(1.5f, __fmul_rn((float)e, delta));
}

// bits of m (8 spikes) -> bf16x8 {0,1} fragment
__device__ __forceinline__ FragU expand_mask(unsigned m) {
    FragU f;
    f.u.x = ((m & 1u)   ? 0x3F80u : 0u) | ((m & 2u)   ? 0x3F800000u : 0u);
    f.u.y = ((m & 4u)   ? 0x3F80u : 0u) | ((m & 8u)   ? 0x3F800000u : 0u);
    f.u.z = ((m & 16u)  ? 0x3F80u : 0u) | ((m & 32u)  ? 0x3F800000u : 0u);
    f.u.w = ((m & 64u)  ? 0x3F80u : 0u) | ((m & 128u) ? 0x3F800000u : 0u);
    return f;
}

// ---------------- k_prep: fused weight-split + router LIF (fat blocks) ------
// grid 256 x 1024. Part A: W -> Whi/Wlo bf16 fragment layout (same math as R5).
// Part B: router LIF tau=2, 6 interleaved chains/thread, exact popcount/256.
__global__ __launch_bounds__(1024) void k_prep(const float* __restrict__ x,
        const float* __restrict__ W1, const float* __restrict__ W2,
        unsigned short* __restrict__ Whif, unsigned short* __restrict__ Wlof,
        float* __restrict__ m) {
    int tid = threadIdx.x;
    int gt = blockIdx.x * 1024 + tid;          // 0..262143
    // ---- Part A: weight split (294912 lane-tasks) ----
    for (int task = gt; task < 294912; task += 262144) {
        int l = task & 63;
        int f = task >> 6;                     // 0..4607
        int osub = f % 24;
        int ksub = (f / 24) % 12;
        int cv = (f / 288) & 1;
        int e = f / 576;
        const float* Wsrc = (cv == 0 ? W1 : W2) + (size_t)e * C_ * C_;
        int o = osub * 16 + (l & 15);
        int c0 = ksub * 32 + (l >> 4) * 8;
        const float* src = Wsrc + (size_t)o * C_ + c0;
        unsigned hw[8], lw[8];
#pragma unroll
        for (int j = 0; j < 8; ++j) {
            float w = src[j];
            unsigned u = __float_as_uint(w);
            unsigned hi = (u + 0x7FFFu + ((u >> 16) & 1u)) >> 16;
            float hf = __uint_as_float(hi << 16);
            float res = __fsub_rn(w, hf);
            unsigned ru = __float_as_uint(res);
            unsigned lo = (ru + 0x7FFFu + ((ru >> 16) & 1u)) >> 16;
            hw[j] = hi & 0xFFFFu;
            lw[j] = lo & 0xFFFFu;
        }
        size_t dst = (size_t)f * 512 + (size_t)l * 8;
        uint4 hv = make_uint4(hw[0] | (hw[1] << 16), hw[2] | (hw[3] << 16),
                              hw[4] | (hw[5] << 16), hw[6] | (hw[7] << 16));
        uint4 lv = make_uint4(lw[0] | (lw[1] << 16), lw[2] | (lw[3] << 16),
                              lw[4] | (lw[5] << 16), lw[6] | (lw[7] << 16));
        *reinterpret_cast<uint4*>(Whif + dst) = hv;
        *reinterpret_cast<uint4*>(Wlof + dst) = lv;
    }
    // ---- Part B: router LIF ----
    int p = tid & 255;
    int slot = tid >> 8;                       // 0..3 (wave-uniform)
    int lane = tid & 63;
    __shared__ int cnt[4][6][T_];
    if (tid < 96) (&cnt[0][0][0])[tid] = 0;
    __syncthreads();
    float v[6];
    int bs[6], cs[6];
#pragma unroll
    for (int it = 0; it < 6; ++it) {
        v[it] = 0.0f;
        int bc = blockIdx.x * 4 + slot + it * 1024;   // covers 0..6143 once
        bs[it] = bc / C_;
        cs[it] = bc % C_;
    }
#pragma unroll
    for (int t = 0; t < T_; ++t) {
        float xv[6];
#pragma unroll
        for (int it = 0; it < 6; ++it)
            xv[it] = x[((t * B_ + bs[it]) * C_ + cs[it]) * HW_ + p];
#pragma unroll
        for (int it = 0; it < 6; ++it) {
            v[it] = __fadd_rn(v[it], __fdiv_rn(__fsub_rn(xv[it], v[it]), 2.0f));
            bool s = (__fsub_rn(v[it], 1.0f) >= 0.0f);
            if (s) v[it] = 0.0f;
            unsigned long long mask = __ballot(s);
            if (lane == 0) atomicAdd(&cnt[slot][it][t], (int)__popcll(mask));
        }
    }
    __syncthreads();
    if (tid < 96) {
        int slot2 = tid / 24;
        int rem = tid % 24;
        int it = rem >> 2, t = rem & 3;
        int bc = blockIdx.x * 4 + slot2 + it * 1024;
        int b = bc / C_, c = bc % C_;
        m[(t * B_ + b) * C_ + c] = (float)cnt[slot2][it][t] * 0.00390625f;
    }
}

// ---------------- conv core: software-pipelined lo/hi MFMA over 12 ksub ------
__device__ __forceinline__ void conv_mfma(const unsigned short* __restrict__ Whif,
                                          const unsigned short* __restrict__ Wlof,
                                          unsigned base,
                                          const unsigned char* __restrict__ sm,
                                          f32x4 (&acc)[3][4],
                                          int tw, int lane, int q, int pl) {
    const unsigned lane8 = (unsigned)lane * 8u;
    const unsigned wbase = base + (unsigned)(tw * 3) * 512u + lane8;
    FragU c0f, c1f, c2f, n0f, n1f, n2f;
    c0f.u = *reinterpret_cast<const uint4*>(Wlof + wbase);
    c1f.u = *reinterpret_cast<const uint4*>(Wlof + wbase + 512u);
    c2f.u = *reinterpret_cast<const uint4*>(Wlof + wbase + 1024u);
#pragma unroll 1
    for (int ksub = 0; ksub < 12; ++ksub) {
        unsigned fo = wbase + (unsigned)ksub * 24u * 512u;
        FragU bf[T_];
#pragma unroll
        for (int t = 0; t < T_; ++t) {
            unsigned mbyte = sm[(t * 16 + pl) * 48 + ksub * 4 + q];
            bf[t] = expand_mask(mbyte);
        }
        n0f.u = *reinterpret_cast<const uint4*>(Whif + fo);
        n1f.u = *reinterpret_cast<const uint4*>(Whif + fo + 512u);
        n2f.u = *reinterpret_cast<const uint4*>(Whif + fo + 1024u);
#pragma unroll
        for (int t = 0; t < T_; ++t) {
            acc[0][t] = __builtin_amdgcn_mfma_f32_16x16x32_bf16(c0f.v, bf[t].v, acc[0][t], 0, 0, 0);
            acc[1][t] = __builtin_amdgcn_mfma_f32_16x16x32_bf16(c1f.v, bf[t].v, acc[1][t], 0, 0, 0);
            acc[2][t] = __builtin_amdgcn_mfma_f32_16x16x32_bf16(c2f.v, bf[t].v, acc[2][t], 0, 0, 0);
        }
        if (ksub < 11) {
            unsigned fn = fo + 24u * 512u;
            c0f.u = *reinterpret_cast<const uint4*>(Wlof + fn);
            c1f.u = *reinterpret_cast<const uint4*>(Wlof + fn + 512u);
            c2f.u = *reinterpret_cast<const uint4*>(Wlof + fn + 1024u);
        }
#pragma unroll
        for (int t = 0; t < T_; ++t) {
            acc[0][t] = __builtin_amdgcn_mfma_f32_16x16x32_bf16(n0f.v, bf[t].v, acc[0][t], 0, 0, 0);
            acc[1][t] = __builtin_amdgcn_mfma_f32_16x16x32_bf16(n1f.v, bf[t].v, acc[1][t], 0, 0, 0);
            acc[2][t] = __builtin_amdgcn_mfma_f32_16x16x32_bf16(n2f.v, bf[t].v, acc[2][t], 0, 0, 0);
        }
    }
}

// ---------------- k_expert: rank-team fused MoE block, LDS-only combine -----
// grid 256 blocks (b x ptile), 1024 threads = 2 teams x 8 waves. Team r runs
// expert rank r end-to-end. All cross-team data moves through lds_sum;
// team0 is the sole writer of out (one coalesced store per element).
__global__ __launch_bounds__(1024, 4) void k_expert(
        const float* __restrict__ x, const float* __restrict__ m,
        const float* __restrict__ rW, const float* __restrict__ rb,
        const float* __restrict__ rbs, const float* __restrict__ rbb,
        const unsigned short* __restrict__ Whif, const unsigned short* __restrict__ Wlof,
        const float* __restrict__ b1, const float* __restrict__ s1sc, const float* __restrict__ s1bi,
        const float* __restrict__ b2, const float* __restrict__ s2sc, const float* __restrict__ s2bi,
        float* __restrict__ out) {
    int blk = blockIdx.x;
    int b = (blk & 7) | (((blk >> 3) & 1) << 3);
    int ptile = blk >> 4;

    __shared__ unsigned char s1m[2][T_ * 16 * 48];
    __shared__ unsigned char s2m[2][T_ * 16 * 48];
    __shared__ float bns[2 * 6 * C_];      // [rank][A1,B1,BB1,A2,B2,BB2][o]
    __shared__ float lds_sum[512 * 49];    // cross-team combine, conflict-free stride
    __shared__ float lg[E_];
    __shared__ float wsl[2];
    __shared__ int esl[2];

    int tid = threadIdx.x;
    int team = tid >> 9;                 // 0 / 1  (wave-uniform)
    int tid2 = tid & 511;                // team-local thread
    int tw = tid2 >> 6;                  // team-local wave 0..7
    int lane = tid & 63;
    int q = lane >> 4;
    int pl = lane & 15;
    int p = ptile * 16 + pl;
    float denom = sqrtf(__fadd_rn(1.0f, 1e-5f));

    // ---- inline route (first wave), identical arithmetic to R5
    if (tid < 64) {
        int combo = tid & 31, half = tid >> 5;
        int e = combo >> 2, t = combo & 3;
        float dot = 0.0f;
        int c0 = half * 192;
        for (int c = 0; c < 192; ++c)
            dot = fmaf(rW[e * C_ + c0 + c], m[(t * B_ + b) * C_ + c0 + c], dot);
        dot += __shfl_down(dot, 32);
        float Ar = __fdiv_rn(rbs[e], denom);
        float lt = __fadd_rn(__fmul_rn(__fadd_rn(dot, rb[e]), Ar), rbb[e]);
        lt = __fadd_rn(lt, __shfl_xor(lt, 1));
        lt = __fadd_rn(lt, __shfl_xor(lt, 2));
        if (half == 0 && t == 0) lg[e] = __fmul_rn(lt, 0.25f);
    }
    __syncthreads();
    if (tid == 0) {
        float pr[E_];
        float mx = lg[0];
        for (int i = 1; i < E_; ++i) mx = fmaxf(mx, lg[i]);
        float s = 0.0f;
        for (int i = 0; i < E_; ++i) { pr[i] = expf(__fsub_rn(lg[i], mx)); s = __fadd_rn(s, pr[i]); }
        for (int i = 0; i < E_; ++i) pr[i] = __fdiv_rn(pr[i], s);
        int i0 = 0;
        for (int i = 1; i < E_; ++i) if (pr[i] > pr[i0]) i0 = i;
        int i1 = (i0 == 0) ? 1 : 0;
        for (int i = 0; i < E_; ++i) if (i != i0 && pr[i] > pr[i1]) i1 = i;
        float s2 = __fadd_rn(pr[i0], pr[i1]);
        wsl[0] = __fdiv_rn(pr[i0], s2);
        wsl[1] = __fdiv_rn(pr[i1], s2);
        esl[0] = i0;
        esl[1] = i1;
    }
    __syncthreads();

    int er = esl[team];
    float wgt = wsl[team];
    float tau = tau_of(er);

    // ---- BN staging for both ranks (768 threads)
    if (tid < 2 * C_) {
        int r_ = tid / C_;
        int o = tid % C_;
        int eo = esl[r_] * C_ + o;
        bns[(r_ * 6 + 0) * C_ + o] = __fdiv_rn(s1sc[eo], denom);
        bns[(r_ * 6 + 1) * C_ + o] = b1[eo];
        bns[(r_ * 6 + 2) * C_ + o] = s1bi[eo];
        bns[(r_ * 6 + 3) * C_ + o] = __fdiv_rn(s2sc[eo], denom);
        bns[(r_ * 6 + 4) * C_ + o] = b2[eo];
        bns[(r_ * 6 + 5) * C_ + o] = s2bi[eo];
    }

    // ---- LIF1 (team-local tau) -> byte masks s1m[team]
#pragma unroll 1
    for (int task = tid2; task < 48 * 16; task += 512) {
        int cb = task >> 4;
        int tpl = task & 15;
        int tp = ptile * 16 + tpl;
        float v[8];
#pragma unroll
        for (int j = 0; j < 8; ++j) v[j] = 0.0f;
#pragma unroll
        for (int t = 0; t < T_; ++t) {
            int gbase = ((t * B_ + b) * C_ + cb * 8) * HW_ + tp;
            unsigned mb = 0;
#pragma unroll
            for (int j = 0; j < 8; ++j) {
                float xv = x[gbase + j * HW_];
                v[j] = __fadd_rn(v[j], __fdiv_rn(__fsub_rn(xv, v[j]), tau));
                if (__fsub_rn(v[j], 1.0f) >= 0.0f) { mb |= (1u << j); v[j] = 0.0f; }
            }
            s1m[team][(t * 16 + tpl) * 48 + cb] = (unsigned char)mb;
        }
    }
    __syncthreads();

    const unsigned base1 = (unsigned)(er * 2) * 12u * 24u * 512u;
    const unsigned base2 = (unsigned)(er * 2 + 1) * 12u * 24u * 512u;

    f32x4 acc[3][4];

    // =================== conv1 (own rank) ===================
#pragma unroll
    for (int os = 0; os < 3; ++os)
#pragma unroll
        for (int t = 0; t < T_; ++t) acc[os][t] = (f32x4)0.0f;

    conv_mfma(Whif, Wlof, base1, &s1m[team][0], acc, tw, lane, q, pl);

    // epilogue: h = x + bn1(y); contrib = wgt*h kept IN acc; LIF2 -> s2m[team];
    // team1 additionally stages contrib in lds_sum.
#pragma unroll
    for (int os = 0; os < 3; ++os) {
        float v2s[4] = {0.f, 0.f, 0.f, 0.f};
#pragma unroll
        for (int t = 0; t < T_; ++t) {
            unsigned nb = 0;
#pragma unroll
            for (int r = 0; r < 4; ++r) {
                int o = tw * 48 + os * 16 + q * 4 + r;
                int gi = ((t * B_ + b) * C_ + o) * HW_ + p;
                float y = acc[os][t][r];
                float h = __fadd_rn(x[gi],
                    __fadd_rn(__fmul_rn(__fadd_rn(y, bns[(team * 6 + 1) * C_ + o]),
                                        bns[(team * 6 + 0) * C_ + o]),
                              bns[(team * 6 + 2) * C_ + o]));
                float contrib = __fmul_rn(wgt, h);
                acc[os][t][r] = contrib;     // hold own contrib in regs
                if (team == 1) lds_sum[tid2 * 49 + os * 16 + t * 4 + r] = contrib;
                v2s[r] = __fadd_rn(v2s[r], __fdiv_rn(__fsub_rn(h, v2s[r]), tau));
                if (__fsub_rn(v2s[r], 1.0f) >= 0.0f) { nb |= (1u << r); v2s[r] = 0.f; }
            }
            unsigned nb_hi = (unsigned)__shfl_down((int)nb, 16);
            if ((q & 1) == 0) {
                int cbyte = tw * 6 + os * 2 + (q >> 1);
                s2m[team][(t * 16 + pl) * 48 + cbyte] = (unsigned char)(nb | (nb_hi << 4));
            }
        }
    }
    __syncthreads();   // A: team1's contrib + s2m visible

    // team0 folds its conv1 contrib into lds_sum
    if (team == 0) {
#pragma unroll
        for (int os = 0; os < 3; ++os)
#pragma unroll
            for (int t = 0; t < T_; ++t)
#pragma unroll
                for (int r = 0; r < 4; ++r) {
                    int li = tid2 * 49 + os * 16 + t * 4 + r;
                    lds_sum[li] = __fadd_rn(lds_sum[li], acc[os][t][r]);
                }
    }
    __syncthreads();   // B: lds_sum = c1 + c0 stable before team1's conv2 adds

    // =================== conv2 (own rank) ===================
#pragma unroll
    for (int os = 0; os < 3; ++os)
#pragma unroll
        for (int t = 0; t < T_; ++t) acc[os][t] = (f32x4)0.0f;

    conv_mfma(Whif, Wlof, base2, &s2m[team][0], acc, tw, lane, q, pl);

    // epilogue: val = wgt*bn2(y); team1: lds_sum += val; team0: keep val in acc
#pragma unroll
    for (int os = 0; os < 3; ++os)
#pragma unroll
        for (int t = 0; t < T_; ++t)
#pragma unroll
            for (int r = 0; r < 4; ++r) {
                int o = tw * 48 + os * 16 + q * 4 + r;
                float y = acc[os][t][r];
                float val = __fmul_rn(wgt,
                    __fadd_rn(__fmul_rn(__fadd_rn(y, bns[(team * 6 + 4) * C_ + o]),
                                        bns[(team * 6 + 3) * C_ + o]),
                              bns[(team * 6 + 5) * C_ + o]));
                if (team == 1) {
                    int li = tid2 * 49 + os * 16 + t * 4 + r;
                    lds_sum[li] = __fadd_rn(lds_sum[li], val);
                } else {
                    acc[os][t][r] = val;
                }
            }
    __syncthreads();   // C: all team1 contributions in lds_sum

    // ---- final: team0 sole writer
    if (team == 0) {
#pragma unroll
        for (int os = 0; os < 3; ++os)
#pragma unroll
            for (int t = 0; t < T_; ++t)
#pragma unroll
                for (int r = 0; r < 4; ++r) {
                    int o = tw * 48 + os * 16 + q * 4 + r;
                    int gi = ((t * B_ + b) * C_ + o) * HW_ + p;
                    float pp = lds_sum[tid2 * 49 + os * 16 + t * 4 + r];
                    out[gi] = __fadd_rn(pp, acc[os][t][r]);
                }
    }
}

extern "C" void kernel_launch(void* const* d_in, const int* in_sizes, int n_in,
                              void* d_out, int out_size, void* d_ws, size_t ws_size,
                              hipStream_t stream) {
    const float* x    = (const float*)d_in[0];
    const float* rW   = (const float*)d_in[1];
    const float* rb   = (const float*)d_in[2];
    const float* rbs  = (const float*)d_in[3];
    const float* rbb  = (const float*)d_in[4];
    const float* W1   = (const float*)d_in[5];
    const float* b1   = (const float*)d_in[6];
    const float* s1sc = (const float*)d_in[7];
    const float* s1bi = (const float*)d_in[8];
    const float* W2   = (const float*)d_in[9];
    const float* b2   = (const float*)d_in[10];
    const float* s2sc = (const float*)d_in[11];
    const float* s2bi = (const float*)d_in[12];
    float* out = (float*)d_out;

    // ws layout: Whif (4718592 B) | Wlof (4718592 B) | m (24576 floats)
    unsigned short* Whif = (unsigned short*)d_ws;
    unsigned short* Wlof = Whif + 2359296;
    float* m = (float*)((char*)d_ws + 9437184);

    hipLaunchKernelGGL(k_prep, dim3(256), dim3(1024), 0, stream,
                       x, W1, W2, Whif, Wlof, m);
    hipLaunchKernelGGL(k_expert, dim3(256), dim3(1024), 0, stream,
                       x, m, rW, rb, rbs, rbb, Whif, Wlof,
                       b1, s1sc, s1bi, b2, s2sc, s2bi, out);
}